// Round 4
// baseline (843.288 us; speedup 1.0000x reference)
//
#include <hip/hip_runtime.h>
#include <hip/hip_bf16.h>

// DCN v2 (modulated deformable 3x3 conv) + BN(eval) + ReLU, fully fused,
// single kernel, NO workspace usage.
// B=4, C=64, O=64, H=W=128, K=9. ALL inputs/outputs are FLOAT32 per the
// reference's setup_inputs (jnp.float32) and the harness dtype contract.
//
// Layouts:
//   x     [4][64][128][128]
//   w_off [27][64][3][3]   oc*576 + c*9 + t
//   wgt   [64][64][3][3]   o*576 + c*9 + t
//   offset channels: tap k -> y-off ch 2k, x-off ch 2k+1, mask ch 18+k
//   (concat(o1,o2) over ch 0..17 is identity; reshape(B,9,2,H,W) interleaves)

#define HH 128
#define WW 128

__global__ __launch_bounds__(256) void DeformConv_14568529068723_kernel(
    const float* __restrict__ x,
    const float* __restrict__ w_off,
    const float* __restrict__ b_off,
    const float* __restrict__ wgt,
    const float* __restrict__ bias,
    const float* __restrict__ gamma,
    const float* __restrict__ beta,
    const float* __restrict__ rmean,
    const float* __restrict__ rvar,
    float* __restrict__ out)
{
    __shared__ float sbuf[128];   // [0..63] scale, [64..127] folded bias

    const int tid = threadIdx.x;
    if (tid < 64) {
        float sc = gamma[tid] * __frsqrt_rn(rvar[tid] + 1e-5f);
        float b2 = (bias[tid] - rmean[tid]) * sc + beta[tid];
        sbuf[tid] = sc;
        sbuf[64 + tid] = b2;
    }
    __syncthreads();

    const int p  = blockIdx.x * 256 + tid;   // global pixel id, lane = pixel
    const int b  = p >> 14;
    const int hw = p & 16383;
    const int h  = hw >> 7;
    const int w  = hw & 127;
    const float* xb = x + ((size_t)b << 20);   // b * 64 * 16384

    // ---- Phase A: 27-channel offset conv (3x3, pad 1), per-lane registers ----
    float acc27[27];
#pragma unroll
    for (int oc = 0; oc < 27; ++oc) acc27[oc] = b_off[oc];

    for (int c = 0; c < 64; ++c) {
        float xv[9];
#pragma unroll
        for (int t = 0; t < 9; ++t) {
            int yy = h + t / 3 - 1;
            int xx = w + t % 3 - 1;
            bool ok = (yy >= 0) & (yy < HH) & (xx >= 0) & (xx < WW);
            int yc = min(max(yy, 0), HH - 1);
            int xc = min(max(xx, 0), WW - 1);
            float v = xb[(c << 14) + yc * WW + xc];
            xv[t] = ok ? v : 0.0f;
        }
#pragma unroll
        for (int oc = 0; oc < 27; ++oc) {
            const float* wr = w_off + oc * 576 + c * 9;  // lane-invariant -> scalar loads
            float a = acc27[oc];
#pragma unroll
            for (int t = 0; t < 9; ++t)
                a = fmaf(xv[t], wr[t], a);
            acc27[oc] = a;
        }
    }

    // ---- Phase B: bilinear setup. Corner validity folded into weights ----
    int   ofs4[9][4];
    float cw[9][4];
#pragma unroll
    for (int k = 0; k < 9; ++k) {
        float o1 = acc27[2 * k];                             // y offset
        float o2 = acc27[2 * k + 1];                         // x offset
        float m  = 1.0f / (1.0f + __expf(-acc27[18 + k]));   // sigmoid(mask)
        float py = (float)(h + k / 3 - 1) + o1;
        float px = (float)(w + k % 3 - 1) + o2;
        float y0f = floorf(py), x0f = floorf(px);
        float dy = py - y0f, dx = px - x0f;
        int y0 = (int)y0f, x0 = (int)x0f;
        int y1 = y0 + 1, x1 = x0 + 1;
        int yc0 = min(max(y0, 0), HH - 1), yc1 = min(max(y1, 0), HH - 1);
        int xc0 = min(max(x0, 0), WW - 1), xc1 = min(max(x1, 0), WW - 1);
        float vy0 = (y0 >= 0 && y0 < HH) ? 1.0f : 0.0f;
        float vy1 = (y1 >= 0 && y1 < HH) ? 1.0f : 0.0f;
        float vx0 = (x0 >= 0 && x0 < WW) ? 1.0f : 0.0f;
        float vx1 = (x1 >= 0 && x1 < WW) ? 1.0f : 0.0f;
        ofs4[k][0] = yc0 * WW + xc0;
        ofs4[k][1] = yc0 * WW + xc1;
        ofs4[k][2] = yc1 * WW + xc0;
        ofs4[k][3] = yc1 * WW + xc1;
        cw[k][0] = (1.0f - dy) * (1.0f - dx) * m * vy0 * vx0;
        cw[k][1] = (1.0f - dy) * dx * m * vy0 * vx1;
        cw[k][2] = dy * (1.0f - dx) * m * vy1 * vx0;
        cw[k][3] = dy * dx * m * vy1 * vx1;
    }

    // ---- Phase C: deformable sampling + 576x64 matvec ----
    float acc[64];
#pragma unroll
    for (int o = 0; o < 64; ++o) acc[o] = 0.0f;

    for (int c = 0; c < 64; ++c) {
        const float* xc = xb + (c << 14);
        float s[9];
#pragma unroll
        for (int k = 0; k < 9; ++k) {
            s[k] = cw[k][0] * xc[ofs4[k][0]]
                 + cw[k][1] * xc[ofs4[k][1]]
                 + cw[k][2] * xc[ofs4[k][2]]
                 + cw[k][3] * xc[ofs4[k][3]];
        }
#pragma unroll
        for (int o = 0; o < 64; ++o) {
            const float* wr = wgt + o * 576 + c * 9;  // lane-invariant -> scalar loads
            float a = acc[o];
#pragma unroll
            for (int k = 0; k < 9; ++k)
                a = fmaf(s[k], wr[k], a);
            acc[o] = a;
        }
    }

    // ---- Phase D: BN + ReLU epilogue, coalesced fp32 stores ----
#pragma unroll
    for (int o = 0; o < 64; ++o) {
        float v = fmaxf(fmaf(acc[o], sbuf[o], sbuf[64 + o]), 0.0f);
        out[(((size_t)(b * 64 + o)) << 14) + hw] = v;
    }
}

extern "C" void kernel_launch(void* const* d_in, const int* in_sizes, int n_in,
                              void* d_out, int out_size, void* d_ws, size_t ws_size,
                              hipStream_t stream) {
    (void)in_sizes; (void)n_in; (void)d_ws; (void)ws_size; (void)out_size;
    const float* x     = (const float*)d_in[0];
    const float* w_off = (const float*)d_in[1];
    const float* b_off = (const float*)d_in[2];
    const float* wgt   = (const float*)d_in[3];
    const float* bias  = (const float*)d_in[4];
    const float* gamma = (const float*)d_in[5];
    const float* beta  = (const float*)d_in[6];
    const float* rmean = (const float*)d_in[7];
    const float* rvar  = (const float*)d_in[8];
    float* outp = (float*)d_out;

    // 4*128*128 pixels / 256 per block = 256 blocks
    DeformConv_14568529068723_kernel<<<dim3(256), dim3(256), 0, stream>>>(
        x, w_off, b_off, wgt, bias, gamma, beta, rmean, rvar, outp);
}

// Round 5
// 768.646 us; speedup vs baseline: 1.0971x; 1.0971x over previous
//
#include <hip/hip_runtime.h>

// DCN v2 (modulated deformable 3x3 conv) + BN(eval) + ReLU, fully fused.
// B=4, C=64, O=64, H=W=128, K=9. fp32 in/out (reference dtypes), fp32 math.
//
// Block = 64 pixels (lane = pixel), 4 waves split input channels 16-each.
// Grid 1024 blocks -> 4096 waves -> 4 blocks/CU (occupancy ~50%), vs round-4's
// 1 block/CU (12%). Cross-wave channel reduction via LDS.
//
// Layouts:
//   x     [4][64][128][128]
//   w_off [27][64][3][3]   oc*576 + c*9 + t   (lane-invariant -> scalar loads)
//   wgt   [64][64][3][3]   o*576 + c*9 + t
//   offset channels: tap k -> y-off ch 2k, x-off ch 2k+1, mask ch 18+k

#define HH 128
#define WW 128

// LDS (floats):
//   [0..6911]    redA[4][27][64] (phase-A partials) / red[4][64][17] (phase-D, aliased)
//   [6912..8639] offs[27][64]
//   [8640..8767] sbuf[128] (BN scale | folded bias)
__global__ __launch_bounds__(256, 4) void DeformConv_14568529068723_kernel(
    const float* __restrict__ x,
    const float* __restrict__ w_off,
    const float* __restrict__ b_off,
    const float* __restrict__ wgt,
    const float* __restrict__ bias,
    const float* __restrict__ gamma,
    const float* __restrict__ beta,
    const float* __restrict__ rmean,
    const float* __restrict__ rvar,
    float* __restrict__ out)
{
    __shared__ float lds[8768];
    float* redA = lds;          // 4*27*64
    float* offs = lds + 6912;   // 27*64
    float* sbuf = lds + 8640;   // 128

    const int tid  = threadIdx.x;
    const int lane = tid & 63;
    const int wv   = tid >> 6;

    if (tid < 64) {
        float sc = gamma[tid] * __frsqrt_rn(rvar[tid] + 1e-5f);
        float b2 = (bias[tid] - rmean[tid]) * sc + beta[tid];
        sbuf[tid] = sc;
        sbuf[64 + tid] = b2;
    }

    const int p0   = blockIdx.x * 64;   // 64 consecutive pixels, same row
    const int b    = p0 >> 14;
    const int rem0 = p0 & 16383;
    const int h    = rem0 >> 7;
    const int w    = (rem0 & 127) + lane;
    const float* xb = x + ((size_t)b << 20);   // b * 64 * 16384
    const int c0 = wv * 16;

    // ---- Phase A: offset conv, wave wv handles channels [c0, c0+16) ----
    float acc27[27];
#pragma unroll
    for (int oc = 0; oc < 27; ++oc) acc27[oc] = 0.0f;

    for (int c = c0; c < c0 + 16; ++c) {
        float xv[9];
#pragma unroll
        for (int t = 0; t < 9; ++t) {
            int yy = h + t / 3 - 1;
            int xx = w + t % 3 - 1;
            bool ok = (yy >= 0) & (yy < HH) & (xx >= 0) & (xx < WW);
            int yc = min(max(yy, 0), HH - 1);
            int xc = min(max(xx, 0), WW - 1);
            float v = xb[(c << 14) + yc * WW + xc];
            xv[t] = ok ? v : 0.0f;
        }
#pragma unroll
        for (int oc = 0; oc < 27; ++oc) {
            const float* wr = w_off + oc * 576 + c * 9;   // lane-invariant
            float a = acc27[oc];
#pragma unroll
            for (int t = 0; t < 9; ++t)
                a = fmaf(xv[t], wr[t], a);
            acc27[oc] = a;
        }
    }
#pragma unroll
    for (int oc = 0; oc < 27; ++oc)
        redA[(wv * 27 + oc) * 64 + lane] = acc27[oc];
    __syncthreads();

    // reduce 4 partials + bias, sigmoid masks -> offs[27][64]
    for (int i = tid; i < 27 * 64; i += 256) {
        int oc = i >> 6;
        float v = redA[i] + redA[1728 + i] + redA[3456 + i] + redA[5184 + i] + b_off[oc];
        if (oc >= 18) v = 1.0f / (1.0f + __expf(-v));
        offs[i] = v;
    }
    __syncthreads();

    // ---- Phase B: bilinear setup (per-lane; corner validity folded into weights) ----
    int   ofs4[9][4];
    float cw[9][4];
#pragma unroll
    for (int k = 0; k < 9; ++k) {
        float o1 = offs[(2 * k) * 64 + lane];
        float o2 = offs[(2 * k + 1) * 64 + lane];
        float m  = offs[(18 + k) * 64 + lane];      // already sigmoided
        float py = (float)(h + k / 3 - 1) + o1;
        float px = (float)(w + k % 3 - 1) + o2;
        float y0f = floorf(py), x0f = floorf(px);
        float dy = py - y0f, dx = px - x0f;
        int y0 = (int)y0f, x0 = (int)x0f;
        int y1 = y0 + 1, x1 = x0 + 1;
        int yc0 = min(max(y0, 0), HH - 1), yc1 = min(max(y1, 0), HH - 1);
        int xc0 = min(max(x0, 0), WW - 1), xc1 = min(max(x1, 0), WW - 1);
        float vy0 = (y0 >= 0 && y0 < HH) ? 1.0f : 0.0f;
        float vy1 = (y1 >= 0 && y1 < HH) ? 1.0f : 0.0f;
        float vx0 = (x0 >= 0 && x0 < WW) ? 1.0f : 0.0f;
        float vx1 = (x1 >= 0 && x1 < WW) ? 1.0f : 0.0f;
        ofs4[k][0] = yc0 * WW + xc0;
        ofs4[k][1] = yc0 * WW + xc1;
        ofs4[k][2] = yc1 * WW + xc0;
        ofs4[k][3] = yc1 * WW + xc1;
        cw[k][0] = (1.0f - dy) * (1.0f - dx) * m * vy0 * vx0;
        cw[k][1] = (1.0f - dy) * dx * m * vy0 * vx1;
        cw[k][2] = dy * (1.0f - dx) * m * vy1 * vx0;
        cw[k][3] = dy * dx * m * vy1 * vx1;
    }

    // ---- Phase C: sampling + matvec over this wave's 16 channels ----
    float acc[64];
#pragma unroll
    for (int o = 0; o < 64; ++o) acc[o] = 0.0f;

    for (int c = c0; c < c0 + 16; ++c) {
        const float* xc = xb + (c << 14);
        float s[9];
#pragma unroll
        for (int k = 0; k < 9; ++k) {
            s[k] = cw[k][0] * xc[ofs4[k][0]]
                 + cw[k][1] * xc[ofs4[k][1]]
                 + cw[k][2] * xc[ofs4[k][2]]
                 + cw[k][3] * xc[ofs4[k][3]];
        }
#pragma unroll
        for (int o = 0; o < 64; ++o) {
            const float* wr = wgt + o * 576 + c * 9;   // lane-invariant
            float a = acc[o];
#pragma unroll
            for (int k = 0; k < 9; ++k)
                a = fmaf(s[k], wr[k], a);
            acc[o] = a;
        }
    }

    // ---- Phase D: cross-wave reduce (4 chunks of 16 outputs) + BN + ReLU ----
    float* red = lds;   // [4][64][17], aliases redA (done with it)
#pragma unroll
    for (int chunk = 0; chunk < 4; ++chunk) {
        __syncthreads();
#pragma unroll
        for (int j = 0; j < 16; ++j)
            red[(wv * 64 + lane) * 17 + j] = acc[chunk * 16 + j];
        __syncthreads();
#pragma unroll
        for (int q = 0; q < 4; ++q) {
            int oo = wv + q * 4;               // wave-uniform
            int o  = chunk * 16 + oo;
            float v = red[(0 * 64 + lane) * 17 + oo]
                    + red[(1 * 64 + lane) * 17 + oo]
                    + red[(2 * 64 + lane) * 17 + oo]
                    + red[(3 * 64 + lane) * 17 + oo];
            v = fmaxf(fmaf(v, sbuf[o], sbuf[64 + o]), 0.0f);
            out[(((size_t)(b * 64 + o)) << 14) + rem0 + lane] = v;
        }
    }
}

extern "C" void kernel_launch(void* const* d_in, const int* in_sizes, int n_in,
                              void* d_out, int out_size, void* d_ws, size_t ws_size,
                              hipStream_t stream) {
    (void)in_sizes; (void)n_in; (void)d_ws; (void)ws_size; (void)out_size;
    const float* x     = (const float*)d_in[0];
    const float* w_off = (const float*)d_in[1];
    const float* b_off = (const float*)d_in[2];
    const float* wgt   = (const float*)d_in[3];
    const float* bias  = (const float*)d_in[4];
    const float* gamma = (const float*)d_in[5];
    const float* beta  = (const float*)d_in[6];
    const float* rmean = (const float*)d_in[7];
    const float* rvar  = (const float*)d_in[8];
    float* outp = (float*)d_out;

    // 4*128*128 pixels / 64 per block = 1024 blocks
    DeformConv_14568529068723_kernel<<<dim3(1024), dim3(256), 0, stream>>>(
        x, w_off, b_off, wgt, bias, gamma, beta, rmean, rvar, outp);
}